// Round 1
// baseline (410.015 us; speedup 1.0000x reference)
//
#include <hip/hip_runtime.h>

#define D 128
#define GROWS 32

// ---------------------------------------------------------------------------
// GCN: out = A_norm @ (x @ W^T) + b, with A_norm = D^-1/2 (A + I) D^-1/2,
// degree computed over src (per reference). Pre-multiply trick: aggregate y
// = x@W^T instead of x, so aggregation writes directly into d_out.
// ws layout: deg/dinv [N f32] | Wt [128x128 f32] | y [N*128 f32] | flag [int]
// ---------------------------------------------------------------------------

__global__ __launch_bounds__(256) void k_setup(const float* __restrict__ W,
                                               const int* __restrict__ ei,
                                               float* __restrict__ deg,
                                               float* __restrict__ Wt,
                                               int* __restrict__ flag,
                                               int N) {
  int i = blockIdx.x * 256 + threadIdx.x;
  if (i < N) deg[i] = 1.0f;  // self-loop weight
  if (i < D * D) {
    int c = i >> 7, k = i & 127;
    Wt[k * D + c] = W[i];  // transpose for coalesced GEMM reads
  }
  if (i == 0) {
    // int64-vs-int32 edge_index layout detection: node ids < 2^31, so if
    // stored as int64 (LE) every odd int32 word is 0.
    flag[0] = (ei[1] == 0 && ei[3] == 0 && ei[5] == 0 && ei[7] == 0) ? 1 : 0;
  }
}

__global__ __launch_bounds__(256) void k_degree(const int* __restrict__ ei,
                                                const float* __restrict__ w,
                                                float* __restrict__ deg,
                                                const int* __restrict__ flag,
                                                int E) {
  int e = blockIdx.x * 256 + threadIdx.x;
  if (e >= E) return;
  int s = flag[0] ? ei[2 * e] : ei[e];
  atomicAdd(&deg[s], w[e]);
}

__global__ __launch_bounds__(256) void k_dinv(float* __restrict__ deg, int N) {
  int i = blockIdx.x * 256 + threadIdx.x;
  if (i < N) deg[i] = rsqrtf(deg[i]);
}

// y = x @ W^T (via Wt), fused epilogue: out = b + dinv^2 * y  (self-loop term)
// 256 threads: 32 col-groups x 8 row-groups; each thread 4 rows x 4 cols.
__global__ __launch_bounds__(256) void k_gemm(const float* __restrict__ x,
                                              const float* __restrict__ Wt,
                                              const float* __restrict__ dinv,
                                              const float* __restrict__ b,
                                              float* __restrict__ y,
                                              float* __restrict__ out,
                                              int N) {
  __shared__ float Xs[GROWS * D];
  const int tid = threadIdx.x;
  const int row0 = blockIdx.x * GROWS;

  // stage 32x128 x-tile (float4, coalesced); zero-pad rows >= N (OOB guard)
  for (int f = tid; f < GROWS * D / 4; f += 256) {
    int r = row0 + ((f * 4) >> 7);
    float4 v = make_float4(0.f, 0.f, 0.f, 0.f);
    if (r < N) v = reinterpret_cast<const float4*>(x)[(size_t)row0 * (D / 4) + f];
    reinterpret_cast<float4*>(Xs)[f] = v;
  }
  __syncthreads();

  const int c0 = (tid & 31) * 4;
  const int r0 = (tid >> 5) * 4;
  float acc[4][4];
#pragma unroll
  for (int i = 0; i < 4; ++i)
#pragma unroll
    for (int j = 0; j < 4; ++j) acc[i][j] = 0.f;

#pragma unroll 4
  for (int k = 0; k < D; ++k) {
    float4 wv = reinterpret_cast<const float4*>(Wt)[(k * D + c0) >> 2];
    float xr[4];
#pragma unroll
    for (int i = 0; i < 4; ++i) xr[i] = Xs[(r0 + i) * D + k];
#pragma unroll
    for (int i = 0; i < 4; ++i) {
      acc[i][0] += xr[i] * wv.x;
      acc[i][1] += xr[i] * wv.y;
      acc[i][2] += xr[i] * wv.z;
      acc[i][3] += xr[i] * wv.w;
    }
  }

  float4 bb = reinterpret_cast<const float4*>(b)[c0 >> 2];
#pragma unroll
  for (int i = 0; i < 4; ++i) {
    int row = row0 + r0 + i;
    if (row < N) {
      float dv = dinv[row];
      float d2 = dv * dv;
      float4 yv = make_float4(acc[i][0], acc[i][1], acc[i][2], acc[i][3]);
      size_t o = ((size_t)row * D + c0) >> 2;
      reinterpret_cast<float4*>(y)[o] = yv;
      float4 ov = make_float4(bb.x + d2 * yv.x, bb.y + d2 * yv.y,
                              bb.z + d2 * yv.z, bb.w + d2 * yv.w);
      reinterpret_cast<float4*>(out)[o] = ov;
    }
  }
}

// per-edge scatter: out[tgt] += w*dinv[s]*dinv[t] * y[src]; 2 edges/block,
// 128 threads (one feature dim) per edge. Scalar loads of e/s/t/w are
// wave-uniform (same address across lanes -> L1 broadcast).
__global__ __launch_bounds__(256) void k_agg(const int* __restrict__ ei,
                                             const float* __restrict__ w,
                                             const float* __restrict__ dinv,
                                             const float* __restrict__ y,
                                             float* __restrict__ out,
                                             const int* __restrict__ flag,
                                             int E) {
  const int tid = threadIdx.x;
  const int e = blockIdx.x * 2 + (tid >> 7);
  const int j = tid & 127;
  if (e >= E) return;
  int s, t;
  if (flag[0]) {
    s = ei[2 * e];
    t = ei[2 * E + 2 * e];
  } else {
    s = ei[e];
    t = ei[E + e];
  }
  float wn = w[e] * dinv[s] * dinv[t];
  atomicAdd(&out[(size_t)t * D + j], wn * y[(size_t)s * D + j]);
}

extern "C" void kernel_launch(void* const* d_in, const int* in_sizes, int n_in,
                              void* d_out, int out_size, void* d_ws, size_t ws_size,
                              hipStream_t stream) {
  const float* x = (const float*)d_in[0];
  const int* ei = (const int*)d_in[1];
  const float* ew = (const float*)d_in[2];
  const float* W = (const float*)d_in[3];
  const float* b = (const float*)d_in[4];
  float* out = (float*)d_out;

  const int N = in_sizes[0] / D;
  const int E = in_sizes[2];

  char* ws = (char*)d_ws;
  float* deg = (float*)ws;  // N floats; becomes dinv in-place
  size_t off = (((size_t)N * 4) + 255) & ~(size_t)255;
  float* Wt = (float*)(ws + off);
  off += (size_t)D * D * 4;
  float* y = (float*)(ws + off);
  off += (size_t)N * D * 4;
  int* flag = (int*)(ws + off);

  int cover = N > D * D ? N : D * D;
  hipLaunchKernelGGL(k_setup, dim3((cover + 255) / 256), dim3(256), 0, stream,
                     W, ei, deg, Wt, flag, N);
  hipLaunchKernelGGL(k_degree, dim3((E + 255) / 256), dim3(256), 0, stream,
                     ei, ew, deg, flag, E);
  hipLaunchKernelGGL(k_dinv, dim3((N + 255) / 256), dim3(256), 0, stream,
                     deg, N);
  hipLaunchKernelGGL(k_gemm, dim3((N + GROWS - 1) / GROWS), dim3(256), 0,
                     stream, x, Wt, deg, b, y, out, N);
  hipLaunchKernelGGL(k_agg, dim3((E + 1) / 2), dim3(256), 0, stream,
                     ei, ew, deg, y, out, flag, E);
}

// Round 2
// 258.278 us; speedup vs baseline: 1.5875x; 1.5875x over previous
//
#include <hip/hip_runtime.h>

#define D 128
#define GROWS 32

// ---------------------------------------------------------------------------
// GCN: out = A_norm @ (x @ W^T) + b. R1 showed per-edge f32 atomics write
// through to HBM (WRITE_SIZE == E*D*4). R2: CSR-by-target + register gather,
// no float atomics.
// ws: deg/dinv[N] | Wt[128^2] | y[N*128] | cnt[N] | cursor[N] | rowptr[N+1]
//     | blocksum | blockoff | edges[E int2] | flag
// ---------------------------------------------------------------------------

__global__ __launch_bounds__(256) void k_setup(const float* __restrict__ W,
                                               const int* __restrict__ ei,
                                               float* __restrict__ deg,
                                               float* __restrict__ Wt,
                                               int* __restrict__ cnt,
                                               int* __restrict__ cursor,
                                               int* __restrict__ flag,
                                               int N) {
  int i = blockIdx.x * 256 + threadIdx.x;
  if (i < N) {
    deg[i] = 1.0f;  // self-loop weight
    cnt[i] = 0;
    cursor[i] = 0;
  }
  if (i < D * D) {
    int c = i >> 7, k = i & 127;
    Wt[k * D + c] = W[i];
  }
  if (i == 0)
    flag[0] = (ei[1] == 0 && ei[3] == 0 && ei[5] == 0 && ei[7] == 0) ? 1 : 0;
}

// one edge pass: deg[src] += w (f32 atomic on N=50k, small), cnt[tgt]++
__global__ __launch_bounds__(256) void k_edge1(const int* __restrict__ ei,
                                               const float* __restrict__ w,
                                               float* __restrict__ deg,
                                               int* __restrict__ cnt,
                                               const int* __restrict__ flag,
                                               int E) {
  int e = blockIdx.x * 256 + threadIdx.x;
  if (e >= E) return;
  int s, t;
  if (flag[0]) { s = ei[2 * e]; t = ei[2 * E + 2 * e]; }
  else         { s = ei[e];     t = ei[E + e]; }
  atomicAdd(&deg[s], w[e]);
  atomicAdd(&cnt[t], 1);
}

__device__ __forceinline__ int wave_incl_scan(int v, int lane) {
#pragma unroll
  for (int o = 1; o < 64; o <<= 1) {
    int t = __shfl_up(v, o);
    if (lane >= o) v += t;
  }
  return v;
}

// per-256-block exclusive scan of cnt -> rowptr (partial), blocksum[bid]=total
// fused: dinv = rsqrt(deg)
__global__ __launch_bounds__(256) void k_scan1(const int* __restrict__ cnt,
                                               int* __restrict__ rowptr,
                                               int* __restrict__ blocksum,
                                               float* __restrict__ deg,
                                               int N) {
  __shared__ int wtot[4];
  int tid = threadIdx.x;
  int i = blockIdx.x * 256 + tid;
  if (i < N) deg[i] = rsqrtf(deg[i]);
  int v = (i < N) ? cnt[i] : 0;
  int lane = tid & 63, wv = tid >> 6;
  int inc = wave_incl_scan(v, lane);
  if (lane == 63) wtot[wv] = inc;
  __syncthreads();
  if (tid == 0) {
    int r = 0;
#pragma unroll
    for (int k = 0; k < 4; ++k) { int t = wtot[k]; wtot[k] = r; r += t; }
  }
  __syncthreads();
  int exc = wtot[wv] + inc - v;
  if (i < N) rowptr[i] = exc;
  if (tid == 255) blocksum[blockIdx.x] = wtot[3] + inc;
}

// single-wave scan of block sums
__global__ __launch_bounds__(64) void k_scan2(int* __restrict__ blocksum,
                                              int* __restrict__ blockoff,
                                              int nb) {
  int lane = threadIdx.x;
  int carry = 0;
  for (int base = 0; base < nb; base += 64) {
    int idx = base + lane;
    int v = (idx < nb) ? blocksum[idx] : 0;
    int inc = wave_incl_scan(v, lane);
    if (idx < nb) blockoff[idx] = carry + inc - v;
    carry += __shfl(inc, 63);
  }
}

__global__ __launch_bounds__(256) void k_scan3(int* __restrict__ rowptr,
                                               const int* __restrict__ blockoff,
                                               int N, int E) {
  int i = blockIdx.x * 256 + threadIdx.x;
  if (i < N) rowptr[i] += blockoff[blockIdx.x];
  if (i == 0) rowptr[N] = E;
}

// scatter edge records {src, wn} into CSR slots (int atomics only)
__global__ __launch_bounds__(256) void k_scatter(const int* __restrict__ ei,
                                                 const float* __restrict__ w,
                                                 const float* __restrict__ dinv,
                                                 const int* __restrict__ rowptr,
                                                 int* __restrict__ cursor,
                                                 int2* __restrict__ edges,
                                                 const int* __restrict__ flag,
                                                 int E) {
  int e = blockIdx.x * 256 + threadIdx.x;
  if (e >= E) return;
  int s, t;
  if (flag[0]) { s = ei[2 * e]; t = ei[2 * E + 2 * e]; }
  else         { s = ei[e];     t = ei[E + e]; }
  float wn = w[e] * dinv[s] * dinv[t];
  int pos = rowptr[t] + atomicAdd(&cursor[t], 1);
  edges[pos] = make_int2(s, __float_as_int(wn));
}

// y = x @ W^T, epilogue writes y only (self-loop handled in gather)
__global__ __launch_bounds__(256) void k_gemm(const float* __restrict__ x,
                                              const float* __restrict__ Wt,
                                              float* __restrict__ y,
                                              int N) {
  __shared__ float Xs[GROWS * D];
  const int tid = threadIdx.x;
  const int row0 = blockIdx.x * GROWS;

  for (int f = tid; f < GROWS * D / 4; f += 256) {
    int r = row0 + ((f * 4) >> 7);
    float4 v = make_float4(0.f, 0.f, 0.f, 0.f);
    if (r < N) v = reinterpret_cast<const float4*>(x)[(size_t)row0 * (D / 4) + f];
    reinterpret_cast<float4*>(Xs)[f] = v;
  }
  __syncthreads();

  const int c0 = (tid & 31) * 4;
  const int r0 = (tid >> 5) * 4;
  float acc[4][4];
#pragma unroll
  for (int i = 0; i < 4; ++i)
#pragma unroll
    for (int j = 0; j < 4; ++j) acc[i][j] = 0.f;

#pragma unroll 4
  for (int k = 0; k < D; ++k) {
    float4 wv = reinterpret_cast<const float4*>(Wt)[(k * D + c0) >> 2];
    float xr[4];
#pragma unroll
    for (int i = 0; i < 4; ++i) xr[i] = Xs[(r0 + i) * D + k];
#pragma unroll
    for (int i = 0; i < 4; ++i) {
      acc[i][0] += xr[i] * wv.x;
      acc[i][1] += xr[i] * wv.y;
      acc[i][2] += xr[i] * wv.z;
      acc[i][3] += xr[i] * wv.w;
    }
  }

#pragma unroll
  for (int i = 0; i < 4; ++i) {
    int row = row0 + r0 + i;
    if (row < N) {
      reinterpret_cast<float4*>(y)[((size_t)row * D + c0) >> 2] =
          make_float4(acc[i][0], acc[i][1], acc[i][2], acc[i][3]);
    }
  }
}

// gather: 64 lanes per node, float2 per lane. out = b + d2*y[i] + sum wn*y[s]
__global__ __launch_bounds__(256) void k_gather(const int* __restrict__ rowptr,
                                                const int2* __restrict__ edges,
                                                const float* __restrict__ y,
                                                const float* __restrict__ dinv,
                                                const float* __restrict__ b,
                                                float* __restrict__ out,
                                                int N) {
  const int tid = threadIdx.x;
  const int node = blockIdx.x * 4 + (tid >> 6);
  const int lane = tid & 63;
  if (node >= N) return;
  const float2* y2 = reinterpret_cast<const float2*>(y);
  float2 bb = reinterpret_cast<const float2*>(b)[lane];
  float dv = dinv[node];
  float d2 = dv * dv;
  float2 yv = y2[(size_t)node * 64 + lane];
  float ax = bb.x + d2 * yv.x;
  float ay = bb.y + d2 * yv.y;

  int e = rowptr[node];
  const int end = rowptr[node + 1];
  // unroll-4: keep 4 independent row loads in flight
  for (; e + 4 <= end; e += 4) {
    int2 e0 = edges[e], e1 = edges[e + 1], e2 = edges[e + 2], e3 = edges[e + 3];
    float2 v0 = y2[(size_t)e0.x * 64 + lane];
    float2 v1 = y2[(size_t)e1.x * 64 + lane];
    float2 v2 = y2[(size_t)e2.x * 64 + lane];
    float2 v3 = y2[(size_t)e3.x * 64 + lane];
    ax += __int_as_float(e0.y) * v0.x; ay += __int_as_float(e0.y) * v0.y;
    ax += __int_as_float(e1.y) * v1.x; ay += __int_as_float(e1.y) * v1.y;
    ax += __int_as_float(e2.y) * v2.x; ay += __int_as_float(e2.y) * v2.y;
    ax += __int_as_float(e3.y) * v3.x; ay += __int_as_float(e3.y) * v3.y;
  }
  for (; e < end; ++e) {
    int2 ed = edges[e];
    float2 sv = y2[(size_t)ed.x * 64 + lane];
    ax += __int_as_float(ed.y) * sv.x;
    ay += __int_as_float(ed.y) * sv.y;
  }
  reinterpret_cast<float2*>(out)[(size_t)node * 64 + lane] = make_float2(ax, ay);
}

extern "C" void kernel_launch(void* const* d_in, const int* in_sizes, int n_in,
                              void* d_out, int out_size, void* d_ws, size_t ws_size,
                              hipStream_t stream) {
  const float* x = (const float*)d_in[0];
  const int* ei = (const int*)d_in[1];
  const float* ew = (const float*)d_in[2];
  const float* W = (const float*)d_in[3];
  const float* b = (const float*)d_in[4];
  float* out = (float*)d_out;

  const int N = in_sizes[0] / D;
  const int E = in_sizes[2];
  const int NB = (N + 255) / 256;

  char* ws = (char*)d_ws;
  size_t off = 0;
  auto alloc = [&](size_t bytes) {
    char* p = ws + off;
    off = (off + bytes + 255) & ~(size_t)255;
    return p;
  };
  float* deg = (float*)alloc((size_t)N * 4);       // becomes dinv
  float* Wt = (float*)alloc((size_t)D * D * 4);
  float* y = (float*)alloc((size_t)N * D * 4);
  int* cnt = (int*)alloc((size_t)N * 4);
  int* cursor = (int*)alloc((size_t)N * 4);
  int* rowptr = (int*)alloc((size_t)(N + 1) * 4);
  int* blocksum = (int*)alloc((size_t)NB * 4);
  int* blockoff = (int*)alloc((size_t)NB * 4);
  int2* edges = (int2*)alloc((size_t)E * 8);
  int* flag = (int*)alloc(4);

  int cover = N > D * D ? N : D * D;
  hipLaunchKernelGGL(k_setup, dim3((cover + 255) / 256), dim3(256), 0, stream,
                     W, ei, deg, Wt, cnt, cursor, flag, N);
  hipLaunchKernelGGL(k_edge1, dim3((E + 255) / 256), dim3(256), 0, stream,
                     ei, ew, deg, cnt, flag, E);
  hipLaunchKernelGGL(k_scan1, dim3(NB), dim3(256), 0, stream,
                     cnt, rowptr, blocksum, deg, N);
  hipLaunchKernelGGL(k_scan2, dim3(1), dim3(64), 0, stream,
                     blocksum, blockoff, NB);
  hipLaunchKernelGGL(k_scan3, dim3(NB), dim3(256), 0, stream,
                     rowptr, blockoff, N, E);
  hipLaunchKernelGGL(k_scatter, dim3((E + 255) / 256), dim3(256), 0, stream,
                     ei, ew, deg, rowptr, cursor, edges, flag, E);
  hipLaunchKernelGGL(k_gemm, dim3((N + GROWS - 1) / GROWS), dim3(256), 0,
                     stream, x, Wt, y, N);
  hipLaunchKernelGGL(k_gather, dim3((N + 3) / 4), dim3(256), 0, stream,
                     rowptr, edges, y, deg, b, out, N);
}

// Round 3
// 227.462 us; speedup vs baseline: 1.8026x; 1.1355x over previous
//
#include <hip/hip_runtime.h>

#define D 128
#define GROWS 32

// ---------------------------------------------------------------------------
// GCN: out = A_norm @ (x @ W^T) + b.
// R1: per-edge f32 atomics write through HBM (300 MB) -> CSR gather.
// R2: edge atomic pass latency-bound (VALUBusy 0.4%) -> R3 fuses the fp32
// GEMM into the same kernel (interleaved blocks) so FMA waves hide atomic
// latency; rank-trick makes scatter atomic-free; gather uses 2 edges/wave
// float4 with dinv[s] pre-applied at scatter.
// ws: deg[N] cnt[N] (contiguous, memset 0) | Wt | y[N*D] | rank[E] |
//     rowptr[N+1] | blocksum | blockoff | edges[E int2] | flag
// ---------------------------------------------------------------------------

__global__ __launch_bounds__(256) void k_setup(const float* __restrict__ W,
                                               const int* __restrict__ ei,
                                               float* __restrict__ Wt,
                                               int* __restrict__ flag) {
  int i = blockIdx.x * 256 + threadIdx.x;
  if (i < D * D) {
    int c = i >> 7, k = i & 127;
    Wt[k * D + c] = W[i];  // transpose for coalesced GEMM reads
  }
  if (i == 0) {
    // int64-vs-int32 edge_index layout detection: ids < 2^31 so int64 (LE)
    // has every odd dword == 0.
    flag[0] = (ei[1] == 0 && ei[3] == 0 && ei[5] == 0 && ei[7] == 0) ? 1 : 0;
  }
}

// Fused: gemm blocks (y = x@W^T) interleaved with edge blocks
// (deg[s] += w f32 atomic; rank[e] = cnt[t]++ int atomic). The gemm waves'
// VALU work hides the edge waves' atomic latency on the same CUs.
__global__ __launch_bounds__(256) void k_fused(const float* __restrict__ x,
                                               const float* __restrict__ Wt,
                                               float* __restrict__ y,
                                               const int* __restrict__ ei,
                                               const float* __restrict__ ew,
                                               float* __restrict__ deg,
                                               int* __restrict__ cnt,
                                               int* __restrict__ rank,
                                               const int* __restrict__ flag,
                                               int N, int E, int Gg, int T) {
  __shared__ float Xs[GROWS * D];
  const int B = blockIdx.x;
  const int tid = threadIdx.x;
  // even interleave: gemm-block count among [0,B) is floor(B*Gg/T)
  const long long gb = ((long long)B * Gg) / T;
  const long long gb1 = ((long long)(B + 1) * Gg) / T;

  if (gb1 > gb) {
    // ---- GEMM block, gemm index = gb ----
    const int row0 = (int)gb * GROWS;
    for (int f = tid; f < GROWS * D / 4; f += 256) {
      int r = row0 + ((f * 4) >> 7);
      float4 v = make_float4(0.f, 0.f, 0.f, 0.f);
      if (r < N)
        v = reinterpret_cast<const float4*>(x)[(size_t)row0 * (D / 4) + f];
      reinterpret_cast<float4*>(Xs)[f] = v;
    }
    __syncthreads();

    const int c0 = (tid & 31) * 4;
    const int r0 = (tid >> 5) * 4;
    float acc[4][4];
#pragma unroll
    for (int i = 0; i < 4; ++i)
#pragma unroll
      for (int j = 0; j < 4; ++j) acc[i][j] = 0.f;

#pragma unroll 4
    for (int k = 0; k < D; ++k) {
      float4 wv = reinterpret_cast<const float4*>(Wt)[(k * D + c0) >> 2];
      float xr[4];
#pragma unroll
      for (int i = 0; i < 4; ++i) xr[i] = Xs[(r0 + i) * D + k];
#pragma unroll
      for (int i = 0; i < 4; ++i) {
        acc[i][0] += xr[i] * wv.x;
        acc[i][1] += xr[i] * wv.y;
        acc[i][2] += xr[i] * wv.z;
        acc[i][3] += xr[i] * wv.w;
      }
    }
#pragma unroll
    for (int i = 0; i < 4; ++i) {
      int row = row0 + r0 + i;
      if (row < N)
        reinterpret_cast<float4*>(y)[((size_t)row * D + c0) >> 2] =
            make_float4(acc[i][0], acc[i][1], acc[i][2], acc[i][3]);
    }
  } else {
    // ---- edge block, edge index = B - gb ----
    const int e = (B - (int)gb) * 256 + tid;
    if (e < E) {
      int s, t;
      if (flag[0]) {
        s = reinterpret_cast<const int2*>(ei)[e].x;
        t = reinterpret_cast<const int2*>(ei)[E + e].x;
      } else {
        s = ei[e];
        t = ei[E + e];
      }
      atomicAdd(&deg[s], ew[e]);
      rank[e] = atomicAdd(&cnt[t], 1);
    }
  }
}

__device__ __forceinline__ int wave_incl_scan(int v, int lane) {
#pragma unroll
  for (int o = 1; o < 64; o <<= 1) {
    int t = __shfl_up(v, o);
    if (lane >= o) v += t;
  }
  return v;
}

// per-block exclusive scan of cnt -> rowptr partial; dinv = rsqrt(deg+1)
__global__ __launch_bounds__(256) void k_scan1(const int* __restrict__ cnt,
                                               int* __restrict__ rowptr,
                                               int* __restrict__ blocksum,
                                               float* __restrict__ deg,
                                               int N) {
  __shared__ int wtot[4];
  int tid = threadIdx.x;
  int i = blockIdx.x * 256 + tid;
  if (i < N) deg[i] = rsqrtf(deg[i] + 1.0f);  // +1 = self-loop weight
  int v = (i < N) ? cnt[i] : 0;
  int lane = tid & 63, wv = tid >> 6;
  int inc = wave_incl_scan(v, lane);
  if (lane == 63) wtot[wv] = inc;
  __syncthreads();
  if (tid == 0) {
    int r = 0;
#pragma unroll
    for (int k = 0; k < 4; ++k) { int t = wtot[k]; wtot[k] = r; r += t; }
  }
  __syncthreads();
  int exc = wtot[wv] + inc - v;
  if (i < N) rowptr[i] = exc;
  if (tid == 255) blocksum[blockIdx.x] = wtot[3] + inc;
}

__global__ __launch_bounds__(64) void k_scan2(int* __restrict__ blocksum,
                                              int* __restrict__ blockoff,
                                              int nb) {
  int lane = threadIdx.x;
  int carry = 0;
  for (int base = 0; base < nb; base += 64) {
    int idx = base + lane;
    int v = (idx < nb) ? blocksum[idx] : 0;
    int inc = wave_incl_scan(v, lane);
    if (idx < nb) blockoff[idx] = carry + inc - v;
    carry += __shfl(inc, 63);
  }
}

__global__ __launch_bounds__(256) void k_scan3(int* __restrict__ rowptr,
                                               const int* __restrict__ blockoff,
                                               int N, int E) {
  int i = blockIdx.x * 256 + threadIdx.x;
  if (i < N) rowptr[i] += blockoff[blockIdx.x];
  if (i == 0) rowptr[N] = E;
}

// atomic-free scatter: pos = rowptr[t] + rank[e]; stores {src, w*dinv[s]}
__global__ __launch_bounds__(256) void k_scatter(const int* __restrict__ ei,
                                                 const float* __restrict__ w,
                                                 const float* __restrict__ dinv,
                                                 const int* __restrict__ rowptr,
                                                 const int* __restrict__ rank,
                                                 int2* __restrict__ edges,
                                                 const int* __restrict__ flag,
                                                 int E) {
  int e = blockIdx.x * 256 + threadIdx.x;
  if (e >= E) return;
  int s, t;
  if (flag[0]) {
    s = reinterpret_cast<const int2*>(ei)[e].x;
    t = reinterpret_cast<const int2*>(ei)[E + e].x;
  } else {
    s = ei[e];
    t = ei[E + e];
  }
  float wn = w[e] * dinv[s];  // dinv[t] applied once per node in gather
  int pos = rowptr[t] + rank[e];
  edges[pos] = make_int2(s, __float_as_int(wn));
}

// gather: 4 nodes/block; per node one wave, halves process alternate edges
// with float4 (32 lanes = one 512B row). out = b + dt*(sum + dt*y[node]).
__global__ __launch_bounds__(256) void k_gather(const int* __restrict__ rowptr,
                                                const int2* __restrict__ edges,
                                                const float* __restrict__ y,
                                                const float* __restrict__ dinv,
                                                const float* __restrict__ b,
                                                float* __restrict__ out,
                                                int N) {
  const int tid = threadIdx.x;
  const int node = blockIdx.x * 4 + (tid >> 6);
  if (node >= N) return;
  const int lane = tid & 63, half = lane >> 5, l32 = lane & 31;
  const float4* y4 = reinterpret_cast<const float4*>(y);

  const float dt = dinv[node];
  const float4 yself = y4[(size_t)node * 32 + l32];  // hoisted for overlap
  const float4 bb = reinterpret_cast<const float4*>(b)[l32];

  float4 acc = make_float4(0.f, 0.f, 0.f, 0.f);
  const int end = rowptr[node + 1];
  int e = rowptr[node] + half;
  // unroll 2 (per half) -> 4 independent row loads in flight per wave
  for (; e + 2 < end; e += 4) {
    int2 e0 = edges[e], e1 = edges[e + 2];
    float4 v0 = y4[(size_t)e0.x * 32 + l32];
    float4 v1 = y4[(size_t)e1.x * 32 + l32];
    float w0 = __int_as_float(e0.y), w1 = __int_as_float(e1.y);
    acc.x += w0 * v0.x; acc.y += w0 * v0.y; acc.z += w0 * v0.z; acc.w += w0 * v0.w;
    acc.x += w1 * v1.x; acc.y += w1 * v1.y; acc.z += w1 * v1.z; acc.w += w1 * v1.w;
  }
  if (e < end) {
    int2 e0 = edges[e];
    float4 v0 = y4[(size_t)e0.x * 32 + l32];
    float w0 = __int_as_float(e0.y);
    acc.x += w0 * v0.x; acc.y += w0 * v0.y; acc.z += w0 * v0.z; acc.w += w0 * v0.w;
  }
  // combine halves into lanes 0-31
  acc.x += __shfl(acc.x, l32 + 32);
  acc.y += __shfl(acc.y, l32 + 32);
  acc.z += __shfl(acc.z, l32 + 32);
  acc.w += __shfl(acc.w, l32 + 32);
  if (half == 0) {
    float4 r;
    r.x = bb.x + dt * (acc.x + dt * yself.x);
    r.y = bb.y + dt * (acc.y + dt * yself.y);
    r.z = bb.z + dt * (acc.z + dt * yself.z);
    r.w = bb.w + dt * (acc.w + dt * yself.w);
    reinterpret_cast<float4*>(out)[(size_t)node * 32 + l32] = r;
  }
}

extern "C" void kernel_launch(void* const* d_in, const int* in_sizes, int n_in,
                              void* d_out, int out_size, void* d_ws, size_t ws_size,
                              hipStream_t stream) {
  const float* x = (const float*)d_in[0];
  const int* ei = (const int*)d_in[1];
  const float* ew = (const float*)d_in[2];
  const float* W = (const float*)d_in[3];
  const float* b = (const float*)d_in[4];
  float* out = (float*)d_out;

  const int N = in_sizes[0] / D;
  const int E = in_sizes[2];
  const int NB = (N + 255) / 256;

  char* ws = (char*)d_ws;
  size_t off = 0;
  auto alloc = [&](size_t bytes) {
    char* p = ws + off;
    off = (off + bytes + 255) & ~(size_t)255;
    return p;
  };
  float* deg = (float*)alloc((size_t)N * 4);   // becomes dinv in scan1
  int* cnt = (int*)alloc((size_t)N * 4);       // contiguous with deg
  float* Wt = (float*)alloc((size_t)D * D * 4);
  float* y = (float*)alloc((size_t)N * D * 4);
  int* rank = (int*)alloc((size_t)E * 4);
  int* rowptr = (int*)alloc((size_t)(N + 1) * 4);
  int* blocksum = (int*)alloc((size_t)NB * 4);
  int* blockoff = (int*)alloc((size_t)NB * 4);
  int2* edges = (int2*)alloc((size_t)E * 8);
  int* flag = (int*)alloc(4);

  // zero deg+cnt (covers the alignment gap too)
  hipMemsetAsync(deg, 0, (size_t)((char*)cnt - (char*)deg) + (size_t)N * 4,
                 stream);
  hipLaunchKernelGGL(k_setup, dim3((D * D + 255) / 256), dim3(256), 0, stream,
                     W, ei, Wt, flag);

  const int Gg = (N + GROWS - 1) / GROWS;
  const int Ge = (E + 255) / 256;
  const int T = Gg + Ge;
  hipLaunchKernelGGL(k_fused, dim3(T), dim3(256), 0, stream,
                     x, Wt, y, ei, ew, deg, cnt, rank, flag, N, E, Gg, T);

  hipLaunchKernelGGL(k_scan1, dim3(NB), dim3(256), 0, stream,
                     cnt, rowptr, blocksum, deg, N);
  hipLaunchKernelGGL(k_scan2, dim3(1), dim3(64), 0, stream,
                     blocksum, blockoff, NB);
  hipLaunchKernelGGL(k_scan3, dim3(NB), dim3(256), 0, stream,
                     rowptr, blockoff, N, E);
  hipLaunchKernelGGL(k_scatter, dim3(Ge), dim3(256), 0, stream,
                     ei, ew, deg, rowptr, rank, edges, flag, E);
  hipLaunchKernelGGL(k_gather, dim3((N + 3) / 4), dim3(256), 0, stream,
                     rowptr, edges, y, deg, b, out, N);
}